// Round 1
// baseline (504.168 us; speedup 1.0000x reference)
//
#include <hip/hip_runtime.h>

// ---------------------------------------------------------------------------
// Pipeline (algebraically restructured from the reference):
//   A[n,:]  = sum_{e: rcv=n} conv_e * node_features[snd_e,:]      [50000,256]
//   c1[n]   = sum_{e: rcv=n} conv_e
//   B[n,:]  = sum_{e2: rcv=n} conv2_e * hedge_features[snd_e,:]   [50000,128]
//   c2[n]   = sum conv2_e
//   out     = (A@Wm + c1*bm) .* (B@Ws + c2*bs)
// ---------------------------------------------------------------------------

// Segmented scatter-accumulate, C=256 channels (float4 per lane, 64 lanes).
// Receivers are sorted, so each wave walks a 64-edge run and flushes its
// register accumulator with atomics only when the receiver id changes.
__global__ __launch_bounds__(256) void scatter_node(
    const float* __restrict__ X,      // [Nsrc,256]
    const int* __restrict__ snd,
    const int* __restrict__ rcv,      // sorted
    const float* __restrict__ conv,
    float* __restrict__ Acc,          // [Mp,256] zero-initialized
    float* __restrict__ csum,         // [Mp]     zero-initialized
    int E)
{
  const int lane = threadIdx.x & 63;
  const int wv = threadIdx.x >> 6;
  long e0 = ((long)blockIdx.x * 4 + wv) * 64;
  if (e0 >= E) return;
  const long e1 = (e0 + 64 < (long)E) ? e0 + 64 : (long)E;

  float4 acc = make_float4(0.f, 0.f, 0.f, 0.f);
  float cacc = 0.f;
  int prev_r = rcv[e0];

  for (long e = e0; e < e1; ++e) {
    const int r = rcv[e];          // wave-uniform broadcast load
    if (r != prev_r) {
      float* dst = Acc + (size_t)prev_r * 256 + lane * 4;
      atomicAdd(dst + 0, acc.x);
      atomicAdd(dst + 1, acc.y);
      atomicAdd(dst + 2, acc.z);
      atomicAdd(dst + 3, acc.w);
      if (lane == 0) atomicAdd(csum + prev_r, cacc);
      acc = make_float4(0.f, 0.f, 0.f, 0.f);
      cacc = 0.f;
      prev_r = r;
    }
    const int s = snd[e];
    const float cv = conv[e];
    const float4 x =
        *reinterpret_cast<const float4*>(X + (size_t)s * 256 + lane * 4);
    acc.x = fmaf(cv, x.x, acc.x);
    acc.y = fmaf(cv, x.y, acc.y);
    acc.z = fmaf(cv, x.z, acc.z);
    acc.w = fmaf(cv, x.w, acc.w);
    cacc += cv;
  }
  float* dst = Acc + (size_t)prev_r * 256 + lane * 4;
  atomicAdd(dst + 0, acc.x);
  atomicAdd(dst + 1, acc.y);
  atomicAdd(dst + 2, acc.z);
  atomicAdd(dst + 3, acc.w);
  if (lane == 0) atomicAdd(csum + prev_r, cacc);
}

// Same, C=128 channels (float2 per lane).
__global__ __launch_bounds__(256) void scatter_hedge(
    const float* __restrict__ X,      // [Nsrc,128]
    const int* __restrict__ snd,
    const int* __restrict__ rcv,      // sorted
    const float* __restrict__ conv,
    float* __restrict__ Acc,          // [Mp,128]
    float* __restrict__ csum,         // [Mp]
    int E)
{
  const int lane = threadIdx.x & 63;
  const int wv = threadIdx.x >> 6;
  long e0 = ((long)blockIdx.x * 4 + wv) * 64;
  if (e0 >= E) return;
  const long e1 = (e0 + 64 < (long)E) ? e0 + 64 : (long)E;

  float2 acc = make_float2(0.f, 0.f);
  float cacc = 0.f;
  int prev_r = rcv[e0];

  for (long e = e0; e < e1; ++e) {
    const int r = rcv[e];
    if (r != prev_r) {
      float* dst = Acc + (size_t)prev_r * 128 + lane * 2;
      atomicAdd(dst + 0, acc.x);
      atomicAdd(dst + 1, acc.y);
      if (lane == 0) atomicAdd(csum + prev_r, cacc);
      acc = make_float2(0.f, 0.f);
      cacc = 0.f;
      prev_r = r;
    }
    const int s = snd[e];
    const float cv = conv[e];
    const float2 x =
        *reinterpret_cast<const float2*>(X + (size_t)s * 128 + lane * 2);
    acc.x = fmaf(cv, x.x, acc.x);
    acc.y = fmaf(cv, x.y, acc.y);
    cacc += cv;
  }
  float* dst = Acc + (size_t)prev_r * 128 + lane * 2;
  atomicAdd(dst + 0, acc.x);
  atomicAdd(dst + 1, acc.y);
  if (lane == 0) atomicAdd(csum + prev_r, cacc);
}

// Fused dual-GEMM + bias + Hadamard:
//   out[m,:] = (A[m,:]@Wm + c1[m]*bm) .* (B[m,:]@Ws + c2[m]*bs)
// Block: 512 threads (8 waves), tile = 64 rows x 256 cols (full N).
// Wave w owns rows [w*8, w*8+8); lane l owns cols [4l, 4l+4).
__global__ __launch_bounds__(512) void gemm_combine(
    const float* __restrict__ A,   // [Mp,256]
    const float* __restrict__ B,   // [Mp,128]
    const float* __restrict__ c1,  // [Mp]
    const float* __restrict__ c2,  // [Mp]
    const float* __restrict__ Wm,  // [256,256]
    const float* __restrict__ bm,  // [256]
    const float* __restrict__ Ws,  // [128,256]
    const float* __restrict__ bs,  // [256]
    float* __restrict__ out,       // [M,256]
    int M)
{
  __shared__ float lT[64][64];     // staged A/B K-chunk (16 KiB)

  const int wv = threadIdx.x >> 6;     // 0..7
  const int lane = threadIdx.x & 63;
  const int col = lane * 4;
  const int m0 = blockIdx.x * 64;

  float accM[8][4];
  float accS[8][4];
#pragma unroll
  for (int r = 0; r < 8; ++r)
#pragma unroll
    for (int j = 0; j < 4; ++j) { accM[r][j] = 0.f; accS[r][j] = 0.f; }

  // ---- accM = A_tile @ Wm  (K = 256, 4 chunks of 64) ----
  for (int kc = 0; kc < 256; kc += 64) {
    __syncthreads();
#pragma unroll
    for (int j = 0; j < 2; ++j) {
      int idx = (int)threadIdx.x + j * 512;   // 0..1023
      int rr = idx >> 4;                      // row 0..63
      int kk = (idx & 15) * 4;                // k offset
      *reinterpret_cast<float4*>(&lT[rr][kk]) =
          *reinterpret_cast<const float4*>(A + (size_t)(m0 + rr) * 256 + kc + kk);
    }
    __syncthreads();
    for (int k = 0; k < 64; k += 4) {
      float4 a[8];
#pragma unroll
      for (int r = 0; r < 8; ++r)
        a[r] = *reinterpret_cast<const float4*>(&lT[wv * 8 + r][k]);
#pragma unroll
      for (int kk = 0; kk < 4; ++kk) {
        const float4 w = *reinterpret_cast<const float4*>(
            Wm + (size_t)(kc + k + kk) * 256 + col);
#pragma unroll
        for (int r = 0; r < 8; ++r) {
          const float av = (&a[r].x)[kk];
          accM[r][0] = fmaf(av, w.x, accM[r][0]);
          accM[r][1] = fmaf(av, w.y, accM[r][1]);
          accM[r][2] = fmaf(av, w.z, accM[r][2]);
          accM[r][3] = fmaf(av, w.w, accM[r][3]);
        }
      }
    }
  }

  // ---- accS = B_tile @ Ws  (K = 128, 2 chunks of 64) ----
  for (int kc = 0; kc < 128; kc += 64) {
    __syncthreads();
#pragma unroll
    for (int j = 0; j < 2; ++j) {
      int idx = (int)threadIdx.x + j * 512;
      int rr = idx >> 4;
      int kk = (idx & 15) * 4;
      *reinterpret_cast<float4*>(&lT[rr][kk]) =
          *reinterpret_cast<const float4*>(B + (size_t)(m0 + rr) * 128 + kc + kk);
    }
    __syncthreads();
    for (int k = 0; k < 64; k += 4) {
      float4 a[8];
#pragma unroll
      for (int r = 0; r < 8; ++r)
        a[r] = *reinterpret_cast<const float4*>(&lT[wv * 8 + r][k]);
#pragma unroll
      for (int kk = 0; kk < 4; ++kk) {
        const float4 w = *reinterpret_cast<const float4*>(
            Ws + (size_t)(kc + k + kk) * 256 + col);
#pragma unroll
        for (int r = 0; r < 8; ++r) {
          const float av = (&a[r].x)[kk];
          accS[r][0] = fmaf(av, w.x, accS[r][0]);
          accS[r][1] = fmaf(av, w.y, accS[r][1]);
          accS[r][2] = fmaf(av, w.z, accS[r][2]);
          accS[r][3] = fmaf(av, w.w, accS[r][3]);
        }
      }
    }
  }

  const float4 bmv = *reinterpret_cast<const float4*>(bm + col);
  const float4 bsv = *reinterpret_cast<const float4*>(bs + col);
#pragma unroll
  for (int r = 0; r < 8; ++r) {
    const int row = m0 + wv * 8 + r;
    if (row < M) {
      const float k1 = c1[row];
      const float k2 = c2[row];
      float4 o;
      o.x = (accM[r][0] + k1 * bmv.x) * (accS[r][0] + k2 * bsv.x);
      o.y = (accM[r][1] + k1 * bmv.y) * (accS[r][1] + k2 * bsv.y);
      o.z = (accM[r][2] + k1 * bmv.z) * (accS[r][2] + k2 * bsv.z);
      o.w = (accM[r][3] + k1 * bmv.w) * (accS[r][3] + k2 * bsv.w);
      *reinterpret_cast<float4*>(out + (size_t)row * 256 + col) = o;
    }
  }
}

extern "C" void kernel_launch(void* const* d_in, const int* in_sizes, int n_in,
                              void* d_out, int out_size, void* d_ws, size_t ws_size,
                              hipStream_t stream) {
  const float* node_features  = (const float*)d_in[0];   // [50000,256]
  const float* hedge_features = (const float*)d_in[1];   // [25000,128]
  const int*   node_senders   = (const int*)d_in[2];     // [E]
  const int*   node_receivers = (const int*)d_in[3];     // [E] sorted
  const float* node_conv      = (const float*)d_in[4];   // [E]
  const int*   h2n_senders    = (const int*)d_in[5];     // [E2]
  const int*   h2n_receivers  = (const int*)d_in[6];     // [E2] sorted
  const float* h2n_conv       = (const float*)d_in[7];   // [E2]
  const float* Wm             = (const float*)d_in[8];   // [256,256]
  const float* bm             = (const float*)d_in[9];   // [256]
  const float* Ws             = (const float*)d_in[10];  // [128,256]
  const float* bs             = (const float*)d_in[11];  // [256]
  float* out = (float*)d_out;

  const int M  = in_sizes[0] / 256;        // 50000 nodes
  const int E  = in_sizes[2];              // 800000
  const int E2 = in_sizes[5];              // 400000
  const int Mp = ((M + 63) / 64) * 64;     // padded rows for GEMM tiles

  // Workspace layout (all float, contiguous): A[Mp,256] B[Mp,128] c1[Mp] c2[Mp]
  float* Acc = (float*)d_ws;
  float* Bcc = Acc + (size_t)Mp * 256;
  float* c1  = Bcc + (size_t)Mp * 128;
  float* c2  = c1 + Mp;
  const size_t zero_bytes = (size_t)Mp * (256 + 128 + 2) * sizeof(float);
  hipMemsetAsync(d_ws, 0, zero_bytes, stream);

  // Each block covers 4 waves * 64 edges = 256 edges.
  scatter_node<<<(E + 255) / 256, 256, 0, stream>>>(
      node_features, node_senders, node_receivers, node_conv, Acc, c1, E);
  scatter_hedge<<<(E2 + 255) / 256, 256, 0, stream>>>(
      hedge_features, h2n_senders, h2n_receivers, h2n_conv, Bcc, c2, E2);
  gemm_combine<<<(M + 63) / 64, 512, 0, stream>>>(
      Acc, Bcc, c1, c2, Wm, bm, Ws, bs, out, M);
}

// Round 2
// 328.199 us; speedup vs baseline: 1.5362x; 1.5362x over previous
//
#include <hip/hip_runtime.h>

// ---------------------------------------------------------------------------
// Pipeline (algebraically restructured from the reference):
//   A[n,:]  = sum_{e: rcv=n} conv_e * node_features[snd_e,:]      [50000,256]
//   c1[n]   = sum_{e: rcv=n} conv_e
//   B[n,:]  = sum_{e2: rcv=n} conv2_e * hedge_features[snd_e,:]   [50000,128]
//   c2[n]   = sum conv2_e
//   out     = (A@Wm + c1*bm) .* (B@Ws + c2*bs)
//
// Receivers are sorted -> convert to CSR row offsets once, then one wave
// owns one node: register accumulate, single non-atomic row store.
// ---------------------------------------------------------------------------

// row_start[n] = first edge index e with rcv[e] >= n  (n in [0, N]).
__global__ __launch_bounds__(256) void build_row_offsets(
    const int* __restrict__ rcv, int E, int N, int* __restrict__ row_start)
{
  const int e = blockIdx.x * blockDim.x + threadIdx.x;
  if (e >= E) return;
  const int c = rcv[e];
  const int p = (e == 0) ? -1 : rcv[e - 1];
  for (int n = p + 1; n <= c; ++n) row_start[n] = e;
  if (e == E - 1) {
    for (int n = c + 1; n <= N; ++n) row_start[n] = E;
  }
}

// One wave per node, C=256 channels (float4 per lane). No atomics.
__global__ __launch_bounds__(256) void scatter_node_seg(
    const float* __restrict__ X,          // [Nsrc,256]
    const int* __restrict__ snd,
    const float* __restrict__ conv,
    const int* __restrict__ row_start,    // [N+1]
    float* __restrict__ A,                // [Mp,256]
    float* __restrict__ csum,             // [Mp]
    int N)
{
  const int lane = threadIdx.x & 63;
  const int node = __builtin_amdgcn_readfirstlane(
      (int)blockIdx.x * 4 + ((int)threadIdx.x >> 6));
  if (node >= N) return;
  const int lo = row_start[node];
  const int hi = row_start[node + 1];

  const float* Xl = X + lane * 4;
  float4 acc = make_float4(0.f, 0.f, 0.f, 0.f);
  float cacc = 0.f;

  int e = lo;
  for (; e + 4 <= hi; e += 4) {
    const int s0 = snd[e + 0], s1 = snd[e + 1], s2 = snd[e + 2], s3 = snd[e + 3];
    const float c0 = conv[e + 0], c1 = conv[e + 1], c2 = conv[e + 2], c3 = conv[e + 3];
    const float4 x0 = *reinterpret_cast<const float4*>(Xl + (size_t)s0 * 256);
    const float4 x1 = *reinterpret_cast<const float4*>(Xl + (size_t)s1 * 256);
    const float4 x2 = *reinterpret_cast<const float4*>(Xl + (size_t)s2 * 256);
    const float4 x3 = *reinterpret_cast<const float4*>(Xl + (size_t)s3 * 256);
    acc.x = fmaf(c0, x0.x, acc.x); acc.y = fmaf(c0, x0.y, acc.y);
    acc.z = fmaf(c0, x0.z, acc.z); acc.w = fmaf(c0, x0.w, acc.w);
    acc.x = fmaf(c1, x1.x, acc.x); acc.y = fmaf(c1, x1.y, acc.y);
    acc.z = fmaf(c1, x1.z, acc.z); acc.w = fmaf(c1, x1.w, acc.w);
    acc.x = fmaf(c2, x2.x, acc.x); acc.y = fmaf(c2, x2.y, acc.y);
    acc.z = fmaf(c2, x2.z, acc.z); acc.w = fmaf(c2, x2.w, acc.w);
    acc.x = fmaf(c3, x3.x, acc.x); acc.y = fmaf(c3, x3.y, acc.y);
    acc.z = fmaf(c3, x3.z, acc.z); acc.w = fmaf(c3, x3.w, acc.w);
    cacc += c0 + c1 + c2 + c3;
  }
  for (; e < hi; ++e) {
    const int s = snd[e];
    const float cv = conv[e];
    const float4 x = *reinterpret_cast<const float4*>(Xl + (size_t)s * 256);
    acc.x = fmaf(cv, x.x, acc.x); acc.y = fmaf(cv, x.y, acc.y);
    acc.z = fmaf(cv, x.z, acc.z); acc.w = fmaf(cv, x.w, acc.w);
    cacc += cv;
  }

  *reinterpret_cast<float4*>(A + (size_t)node * 256 + lane * 4) = acc;
  if (lane == 0) csum[node] = cacc;
}

// One wave per node, C=128 channels (float2 per lane). No atomics.
__global__ __launch_bounds__(256) void scatter_hedge_seg(
    const float* __restrict__ X,          // [Nsrc,128]
    const int* __restrict__ snd,
    const float* __restrict__ conv,
    const int* __restrict__ row_start,    // [N+1]
    float* __restrict__ B,                // [Mp,128]
    float* __restrict__ csum,             // [Mp]
    int N)
{
  const int lane = threadIdx.x & 63;
  const int node = __builtin_amdgcn_readfirstlane(
      (int)blockIdx.x * 4 + ((int)threadIdx.x >> 6));
  if (node >= N) return;
  const int lo = row_start[node];
  const int hi = row_start[node + 1];

  const float* Xl = X + lane * 2;
  float2 acc = make_float2(0.f, 0.f);
  float cacc = 0.f;

  int e = lo;
  for (; e + 8 <= hi; e += 8) {
    int s[8]; float cv[8]; float2 x[8];
#pragma unroll
    for (int j = 0; j < 8; ++j) s[j] = snd[e + j];
#pragma unroll
    for (int j = 0; j < 8; ++j) cv[j] = conv[e + j];
#pragma unroll
    for (int j = 0; j < 8; ++j)
      x[j] = *reinterpret_cast<const float2*>(Xl + (size_t)s[j] * 128);
#pragma unroll
    for (int j = 0; j < 8; ++j) {
      acc.x = fmaf(cv[j], x[j].x, acc.x);
      acc.y = fmaf(cv[j], x[j].y, acc.y);
      cacc += cv[j];
    }
  }
  for (; e < hi; ++e) {
    const int s = snd[e];
    const float cv = conv[e];
    const float2 x = *reinterpret_cast<const float2*>(Xl + (size_t)s * 128);
    acc.x = fmaf(cv, x.x, acc.x);
    acc.y = fmaf(cv, x.y, acc.y);
    cacc += cv;
  }

  *reinterpret_cast<float2*>(B + (size_t)node * 128 + lane * 2) = acc;
  if (lane == 0) csum[node] = cacc;
}

// Fused dual-GEMM + bias + Hadamard:
//   out[m,:] = (A[m,:]@Wm + c1[m]*bm) .* (B[m,:]@Ws + c2[m]*bs)
// Block: 512 threads (8 waves), tile = 64 rows x 256 cols (full N).
__global__ __launch_bounds__(512) void gemm_combine(
    const float* __restrict__ A,   // [Mp,256]
    const float* __restrict__ B,   // [Mp,128]
    const float* __restrict__ c1,  // [Mp]
    const float* __restrict__ c2,  // [Mp]
    const float* __restrict__ Wm,  // [256,256]
    const float* __restrict__ bm,  // [256]
    const float* __restrict__ Ws,  // [128,256]
    const float* __restrict__ bs,  // [256]
    float* __restrict__ out,       // [M,256]
    int M)
{
  __shared__ float lT[64][64];     // staged A/B K-chunk (16 KiB)

  const int wv = threadIdx.x >> 6;     // 0..7
  const int lane = threadIdx.x & 63;
  const int col = lane * 4;
  const int m0 = blockIdx.x * 64;

  float accM[8][4];
  float accS[8][4];
#pragma unroll
  for (int r = 0; r < 8; ++r)
#pragma unroll
    for (int j = 0; j < 4; ++j) { accM[r][j] = 0.f; accS[r][j] = 0.f; }

  // ---- accM = A_tile @ Wm  (K = 256, 4 chunks of 64) ----
  for (int kc = 0; kc < 256; kc += 64) {
    __syncthreads();
#pragma unroll
    for (int j = 0; j < 2; ++j) {
      int idx = (int)threadIdx.x + j * 512;   // 0..1023
      int rr = idx >> 4;                      // row 0..63
      int kk = (idx & 15) * 4;                // k offset
      *reinterpret_cast<float4*>(&lT[rr][kk]) =
          *reinterpret_cast<const float4*>(A + (size_t)(m0 + rr) * 256 + kc + kk);
    }
    __syncthreads();
    for (int k = 0; k < 64; k += 4) {
      float4 a[8];
#pragma unroll
      for (int r = 0; r < 8; ++r)
        a[r] = *reinterpret_cast<const float4*>(&lT[wv * 8 + r][k]);
#pragma unroll
      for (int kk = 0; kk < 4; ++kk) {
        const float4 w = *reinterpret_cast<const float4*>(
            Wm + (size_t)(kc + k + kk) * 256 + col);
#pragma unroll
        for (int r = 0; r < 8; ++r) {
          const float av = (&a[r].x)[kk];
          accM[r][0] = fmaf(av, w.x, accM[r][0]);
          accM[r][1] = fmaf(av, w.y, accM[r][1]);
          accM[r][2] = fmaf(av, w.z, accM[r][2]);
          accM[r][3] = fmaf(av, w.w, accM[r][3]);
        }
      }
    }
  }

  // ---- accS = B_tile @ Ws  (K = 128, 2 chunks of 64) ----
  for (int kc = 0; kc < 128; kc += 64) {
    __syncthreads();
#pragma unroll
    for (int j = 0; j < 2; ++j) {
      int idx = (int)threadIdx.x + j * 512;
      int rr = idx >> 4;
      int kk = (idx & 15) * 4;
      *reinterpret_cast<float4*>(&lT[rr][kk]) =
          *reinterpret_cast<const float4*>(B + (size_t)(m0 + rr) * 128 + kc + kk);
    }
    __syncthreads();
    for (int k = 0; k < 64; k += 4) {
      float4 a[8];
#pragma unroll
      for (int r = 0; r < 8; ++r)
        a[r] = *reinterpret_cast<const float4*>(&lT[wv * 8 + r][k]);
#pragma unroll
      for (int kk = 0; kk < 4; ++kk) {
        const float4 w = *reinterpret_cast<const float4*>(
            Ws + (size_t)(kc + k + kk) * 256 + col);
#pragma unroll
        for (int r = 0; r < 8; ++r) {
          const float av = (&a[r].x)[kk];
          accS[r][0] = fmaf(av, w.x, accS[r][0]);
          accS[r][1] = fmaf(av, w.y, accS[r][1]);
          accS[r][2] = fmaf(av, w.z, accS[r][2]);
          accS[r][3] = fmaf(av, w.w, accS[r][3]);
        }
      }
    }
  }

  const float4 bmv = *reinterpret_cast<const float4*>(bm + col);
  const float4 bsv = *reinterpret_cast<const float4*>(bs + col);
#pragma unroll
  for (int r = 0; r < 8; ++r) {
    const int row = m0 + wv * 8 + r;
    if (row < M) {
      const float k1 = c1[row];
      const float k2 = c2[row];
      float4 o;
      o.x = (accM[r][0] + k1 * bmv.x) * (accS[r][0] + k2 * bsv.x);
      o.y = (accM[r][1] + k1 * bmv.y) * (accS[r][1] + k2 * bsv.y);
      o.z = (accM[r][2] + k1 * bmv.z) * (accS[r][2] + k2 * bsv.z);
      o.w = (accM[r][3] + k1 * bmv.w) * (accS[r][3] + k2 * bsv.w);
      *reinterpret_cast<float4*>(out + (size_t)row * 256 + col) = o;
    }
  }
}

extern "C" void kernel_launch(void* const* d_in, const int* in_sizes, int n_in,
                              void* d_out, int out_size, void* d_ws, size_t ws_size,
                              hipStream_t stream) {
  const float* node_features  = (const float*)d_in[0];   // [50000,256]
  const float* hedge_features = (const float*)d_in[1];   // [25000,128]
  const int*   node_senders   = (const int*)d_in[2];     // [E]
  const int*   node_receivers = (const int*)d_in[3];     // [E] sorted
  const float* node_conv      = (const float*)d_in[4];   // [E]
  const int*   h2n_senders    = (const int*)d_in[5];     // [E2]
  const int*   h2n_receivers  = (const int*)d_in[6];     // [E2] sorted
  const float* h2n_conv       = (const float*)d_in[7];   // [E2]
  const float* Wm             = (const float*)d_in[8];   // [256,256]
  const float* bm             = (const float*)d_in[9];   // [256]
  const float* Ws             = (const float*)d_in[10];  // [128,256]
  const float* bs             = (const float*)d_in[11];  // [256]
  float* out = (float*)d_out;

  const int M  = in_sizes[0] / 256;        // 50000 nodes
  const int E  = in_sizes[2];              // 800000
  const int E2 = in_sizes[5];              // 400000
  const int Mp = ((M + 63) / 64) * 64;     // padded rows for GEMM tiles

  // Workspace layout: A[Mp,256] B[Mp,128] c1[Mp] c2[Mp] ro1[M+1] ro2[M+1]
  float* Acc = (float*)d_ws;
  float* Bcc = Acc + (size_t)Mp * 256;
  float* c1  = Bcc + (size_t)Mp * 128;
  float* c2  = c1 + Mp;
  int*   ro1 = (int*)(c2 + Mp);
  int*   ro2 = ro1 + (M + 1);

  build_row_offsets<<<(E + 255) / 256, 256, 0, stream>>>(
      node_receivers, E, M, ro1);
  build_row_offsets<<<(E2 + 255) / 256, 256, 0, stream>>>(
      h2n_receivers, E2, M, ro2);

  // One wave per node: 4 waves per block.
  scatter_node_seg<<<(M + 3) / 4, 256, 0, stream>>>(
      node_features, node_senders, node_conv, ro1, Acc, c1, M);
  scatter_hedge_seg<<<(M + 3) / 4, 256, 0, stream>>>(
      hedge_features, h2n_senders, h2n_conv, ro2, Bcc, c2, M);

  gemm_combine<<<(M + 63) / 64, 512, 0, stream>>>(
      Acc, Bcc, c1, c2, Wm, bm, Ws, bs, out, M);
}

// Round 3
// 225.337 us; speedup vs baseline: 2.2374x; 1.4565x over previous
//
#include <hip/hip_runtime.h>

// ---------------------------------------------------------------------------
// Pipeline (algebraically restructured from the reference):
//   A[n,:]  = sum_{e: rcv=n} conv_e * node_features[snd_e,:]   (bf16, [Mp,256])
//   c1[n]   = sum_{e: rcv=n} conv_e                            (f32)
//   B[n,:]  = sum_{e2} conv2_e * hedge_features[snd_e,:]       (bf16, [Mp,128])
//   c2[n]   = sum conv2_e
//   out     = (A@Wm + c1*bm) .* (B@Ws + c2*bs)   -- bf16 MFMA, f32 accum
// ---------------------------------------------------------------------------

typedef __attribute__((ext_vector_type(8))) short bf16x8;
typedef __attribute__((ext_vector_type(4))) float f32x4;

static __device__ __forceinline__ unsigned short f2bf(float f) {
  unsigned u = __float_as_uint(f);
  u += 0x7fff + ((u >> 16) & 1);          // round-to-nearest-even
  return (unsigned short)(u >> 16);
}

// row_start[n] = first edge index e with rcv[e] >= n  (n in [0, N]).
__global__ __launch_bounds__(256) void build_row_offsets(
    const int* __restrict__ rcv, int E, int N, int* __restrict__ row_start)
{
  const int e = blockIdx.x * blockDim.x + threadIdx.x;
  if (e >= E) return;
  const int c = rcv[e];
  const int p = (e == 0) ? -1 : rcv[e - 1];
  for (int n = p + 1; n <= c; ++n) row_start[n] = e;
  if (e == E - 1) {
    for (int n = c + 1; n <= N; ++n) row_start[n] = E;
  }
}

// W[K][N] f32 -> WT[N][K] bf16 via LDS 32x32 tile transpose.
__global__ __launch_bounds__(256) void transpose_to_bf16(
    const float* __restrict__ W, unsigned short* __restrict__ WT, int K, int N)
{
  __shared__ float t[32][33];
  const int tx = threadIdx.x & 31, ty = threadIdx.x >> 5;   // 32 x 8
  const int n0 = blockIdx.x * 32, k0 = blockIdx.y * 32;
#pragma unroll
  for (int i = 0; i < 32; i += 8)
    t[ty + i][tx] = W[(size_t)(k0 + ty + i) * N + n0 + tx];
  __syncthreads();
#pragma unroll
  for (int i = 0; i < 32; i += 8)
    WT[(size_t)(n0 + ty + i) * K + k0 + tx] = f2bf(t[tx][ty + i]);
}

// One wave per node, C=256 channels (float4 per lane). No atomics; bf16 out.
__global__ __launch_bounds__(256) void scatter_node_seg(
    const float* __restrict__ X,          // [Nsrc,256]
    const int* __restrict__ snd,
    const float* __restrict__ conv,
    const int* __restrict__ row_start,    // [N+1]
    unsigned short* __restrict__ A,       // [Mp,256] bf16
    float* __restrict__ csum,             // [Mp]
    int N)
{
  const int lane = threadIdx.x & 63;
  const int node = __builtin_amdgcn_readfirstlane(
      (int)blockIdx.x * 4 + ((int)threadIdx.x >> 6));
  if (node >= N) return;
  const int lo = row_start[node];
  const int hi = row_start[node + 1];

  const float* Xl = X + lane * 4;
  float4 acc = make_float4(0.f, 0.f, 0.f, 0.f);
  float cacc = 0.f;

  int e = lo;
  for (; e + 4 <= hi; e += 4) {
    const int s0 = snd[e + 0], s1 = snd[e + 1], s2 = snd[e + 2], s3 = snd[e + 3];
    const float c0 = conv[e + 0], c1 = conv[e + 1], c2 = conv[e + 2], c3 = conv[e + 3];
    const float4 x0 = *reinterpret_cast<const float4*>(Xl + (size_t)s0 * 256);
    const float4 x1 = *reinterpret_cast<const float4*>(Xl + (size_t)s1 * 256);
    const float4 x2 = *reinterpret_cast<const float4*>(Xl + (size_t)s2 * 256);
    const float4 x3 = *reinterpret_cast<const float4*>(Xl + (size_t)s3 * 256);
    acc.x = fmaf(c0, x0.x, acc.x); acc.y = fmaf(c0, x0.y, acc.y);
    acc.z = fmaf(c0, x0.z, acc.z); acc.w = fmaf(c0, x0.w, acc.w);
    acc.x = fmaf(c1, x1.x, acc.x); acc.y = fmaf(c1, x1.y, acc.y);
    acc.z = fmaf(c1, x1.z, acc.z); acc.w = fmaf(c1, x1.w, acc.w);
    acc.x = fmaf(c2, x2.x, acc.x); acc.y = fmaf(c2, x2.y, acc.y);
    acc.z = fmaf(c2, x2.z, acc.z); acc.w = fmaf(c2, x2.w, acc.w);
    acc.x = fmaf(c3, x3.x, acc.x); acc.y = fmaf(c3, x3.y, acc.y);
    acc.z = fmaf(c3, x3.z, acc.z); acc.w = fmaf(c3, x3.w, acc.w);
    cacc += c0 + c1 + c2 + c3;
  }
  for (; e < hi; ++e) {
    const int s = snd[e];
    const float cv = conv[e];
    const float4 x = *reinterpret_cast<const float4*>(Xl + (size_t)s * 256);
    acc.x = fmaf(cv, x.x, acc.x); acc.y = fmaf(cv, x.y, acc.y);
    acc.z = fmaf(cv, x.z, acc.z); acc.w = fmaf(cv, x.w, acc.w);
    cacc += cv;
  }

  *reinterpret_cast<ushort4*>(A + (size_t)node * 256 + lane * 4) =
      make_ushort4(f2bf(acc.x), f2bf(acc.y), f2bf(acc.z), f2bf(acc.w));
  if (lane == 0) csum[node] = cacc;
}

// One wave per node, C=128 channels (float2 per lane). No atomics; bf16 out.
__global__ __launch_bounds__(256) void scatter_hedge_seg(
    const float* __restrict__ X,          // [Nsrc,128]
    const int* __restrict__ snd,
    const float* __restrict__ conv,
    const int* __restrict__ row_start,    // [N+1]
    unsigned short* __restrict__ B,       // [Mp,128] bf16
    float* __restrict__ csum,             // [Mp]
    int N)
{
  const int lane = threadIdx.x & 63;
  const int node = __builtin_amdgcn_readfirstlane(
      (int)blockIdx.x * 4 + ((int)threadIdx.x >> 6));
  if (node >= N) return;
  const int lo = row_start[node];
  const int hi = row_start[node + 1];

  const float* Xl = X + lane * 2;
  float2 acc = make_float2(0.f, 0.f);
  float cacc = 0.f;

  int e = lo;
  for (; e + 8 <= hi; e += 8) {
    int s[8]; float cv[8]; float2 x[8];
#pragma unroll
    for (int j = 0; j < 8; ++j) s[j] = snd[e + j];
#pragma unroll
    for (int j = 0; j < 8; ++j) cv[j] = conv[e + j];
#pragma unroll
    for (int j = 0; j < 8; ++j)
      x[j] = *reinterpret_cast<const float2*>(Xl + (size_t)s[j] * 128);
#pragma unroll
    for (int j = 0; j < 8; ++j) {
      acc.x = fmaf(cv[j], x[j].x, acc.x);
      acc.y = fmaf(cv[j], x[j].y, acc.y);
      cacc += cv[j];
    }
  }
  for (; e < hi; ++e) {
    const int s = snd[e];
    const float cv = conv[e];
    const float2 x = *reinterpret_cast<const float2*>(Xl + (size_t)s * 128);
    acc.x = fmaf(cv, x.x, acc.x);
    acc.y = fmaf(cv, x.y, acc.y);
    cacc += cv;
  }

  *reinterpret_cast<ushort2*>(B + (size_t)node * 128 + lane * 2) =
      make_ushort2(f2bf(acc.x), f2bf(acc.y));
  if (lane == 0) csum[node] = cacc;
}

// MFMA dual-GEMM + bias + Hadamard. Block = 512 threads = 8 waves (2m x 4n).
// Block tile 64 rows x 256 cols; wave tile 32 rows x 64 cols
// = 2 m-subtiles x 4 n-subtiles of 16x16. No LDS; operands stream from L2.
// mfma_f32_16x16x32_bf16 fragments:
//   A-frag: row = lane&15, k = 8*(lane>>4) + j  (contiguous 16B from row-major)
//   B-frag: col = lane&15, k = 8*(lane>>4) + j  (contiguous 16B from WT)
//   C/D   : col = lane&15, row = 4*(lane>>4) + reg   [m89-verified]
__global__ __launch_bounds__(512) void gemm_combine_mfma(
    const unsigned short* __restrict__ A,    // [Mp,256] bf16
    const unsigned short* __restrict__ B,    // [Mp,128] bf16
    const float* __restrict__ c1,            // [Mp]
    const float* __restrict__ c2,            // [Mp]
    const unsigned short* __restrict__ WmT,  // [256,256] bf16 (N-major)
    const float* __restrict__ bm,            // [256]
    const unsigned short* __restrict__ WsT,  // [256,128] bf16 (N-major)
    const float* __restrict__ bs,            // [256]
    float* __restrict__ out,                 // [M,256]
    int M)
{
  const int lane = threadIdx.x & 63;
  const int wv = threadIdx.x >> 6;
  const int wvm = wv >> 2;            // 0..1
  const int wvn = wv & 3;             // 0..3
  const int l15 = lane & 15;
  const int lg  = lane >> 4;          // 0..3
  const int m0 = blockIdx.x * 64;

  const int rowA = m0 + wvm * 32 + l15;     // + ms*16
  const int colW = wvn * 64 + l15;          // + n*16

  f32x4 accM[2][4];
  f32x4 accS[2][4];
#pragma unroll
  for (int ms = 0; ms < 2; ++ms)
#pragma unroll
    for (int n = 0; n < 4; ++n) {
      accM[ms][n] = (f32x4)0.f;
      accS[ms][n] = (f32x4)0.f;
    }

  // ---- accM = A @ Wm, K = 256 ----
#pragma unroll
  for (int kc = 0; kc < 256; kc += 32) {
    const int ko = kc + lg * 8;
    const bf16x8 a0 = *reinterpret_cast<const bf16x8*>(A + (size_t)rowA * 256 + ko);
    const bf16x8 a1 = *reinterpret_cast<const bf16x8*>(A + (size_t)(rowA + 16) * 256 + ko);
#pragma unroll
    for (int n = 0; n < 4; ++n) {
      const bf16x8 w = *reinterpret_cast<const bf16x8*>(
          WmT + (size_t)(colW + n * 16) * 256 + ko);
      accM[0][n] = __builtin_amdgcn_mfma_f32_16x16x32_bf16(a0, w, accM[0][n], 0, 0, 0);
      accM[1][n] = __builtin_amdgcn_mfma_f32_16x16x32_bf16(a1, w, accM[1][n], 0, 0, 0);
    }
  }

  // ---- accS = B @ Ws, K = 128 ----
#pragma unroll
  for (int kc = 0; kc < 128; kc += 32) {
    const int ko = kc + lg * 8;
    const bf16x8 b0 = *reinterpret_cast<const bf16x8*>(B + (size_t)rowA * 128 + ko);
    const bf16x8 b1 = *reinterpret_cast<const bf16x8*>(B + (size_t)(rowA + 16) * 128 + ko);
#pragma unroll
    for (int n = 0; n < 4; ++n) {
      const bf16x8 w = *reinterpret_cast<const bf16x8*>(
          WsT + (size_t)(colW + n * 16) * 128 + ko);
      accS[0][n] = __builtin_amdgcn_mfma_f32_16x16x32_bf16(b0, w, accS[0][n], 0, 0, 0);
      accS[1][n] = __builtin_amdgcn_mfma_f32_16x16x32_bf16(b1, w, accS[1][n], 0, 0, 0);
    }
  }

  // ---- epilogue: (accM + c1*bm) .* (accS + c2*bs) ----
  float bmv[4], bsv[4];
#pragma unroll
  for (int n = 0; n < 4; ++n) {
    bmv[n] = bm[colW + n * 16];
    bsv[n] = bs[colW + n * 16];
  }
#pragma unroll
  for (int ms = 0; ms < 2; ++ms) {
    const int rbase = m0 + wvm * 32 + ms * 16 + lg * 4;
#pragma unroll
    for (int r = 0; r < 4; ++r) {
      const int row = rbase + r;
      if (row < M) {
        const float k1 = c1[row];
        const float k2 = c2[row];
#pragma unroll
        for (int n = 0; n < 4; ++n) {
          const int col = colW + n * 16;
          const float mv = accM[ms][n][r] + k1 * bmv[n];
          const float sv = accS[ms][n][r] + k2 * bsv[n];
          out[(size_t)row * 256 + col] = mv * sv;
        }
      }
    }
  }
}

extern "C" void kernel_launch(void* const* d_in, const int* in_sizes, int n_in,
                              void* d_out, int out_size, void* d_ws, size_t ws_size,
                              hipStream_t stream) {
  const float* node_features  = (const float*)d_in[0];   // [50000,256]
  const float* hedge_features = (const float*)d_in[1];   // [25000,128]
  const int*   node_senders   = (const int*)d_in[2];     // [E]
  const int*   node_receivers = (const int*)d_in[3];     // [E] sorted
  const float* node_conv      = (const float*)d_in[4];   // [E]
  const int*   h2n_senders    = (const int*)d_in[5];     // [E2]
  const int*   h2n_receivers  = (const int*)d_in[6];     // [E2] sorted
  const float* h2n_conv       = (const float*)d_in[7];   // [E2]
  const float* Wm             = (const float*)d_in[8];   // [256,256]
  const float* bm             = (const float*)d_in[9];   // [256]
  const float* Ws             = (const float*)d_in[10];  // [128,256]
  const float* bs             = (const float*)d_in[11];  // [256]
  float* out = (float*)d_out;

  const int M  = in_sizes[0] / 256;        // 50000 nodes
  const int E  = in_sizes[2];              // 800000
  const int E2 = in_sizes[5];              // 400000
  const int Mp = ((M + 63) / 64) * 64;     // padded rows for GEMM tiles

  // Workspace layout:
  //   A_bf16 [Mp,256] | B_bf16 [Mp,128] | WmT_bf16 [256,256] | WsT_bf16 [256,128]
  //   | c1 f32 [Mp] | c2 f32 [Mp] | ro1 [M+1] | ro2 [M+1]
  unsigned short* Ab  = (unsigned short*)d_ws;
  unsigned short* Bb  = Ab + (size_t)Mp * 256;
  unsigned short* WmT = Bb + (size_t)Mp * 128;
  unsigned short* WsT = WmT + 256 * 256;
  float* c1 = (float*)(WsT + 256 * 128);
  float* c2 = c1 + Mp;
  int*   ro1 = (int*)(c2 + Mp);
  int*   ro2 = ro1 + (M + 1);

  build_row_offsets<<<(E + 255) / 256, 256, 0, stream>>>(
      node_receivers, E, M, ro1);
  build_row_offsets<<<(E2 + 255) / 256, 256, 0, stream>>>(
      h2n_receivers, E2, M, ro2);

  transpose_to_bf16<<<dim3(256 / 32, 256 / 32), 256, 0, stream>>>(
      Wm, WmT, 256, 256);
  transpose_to_bf16<<<dim3(256 / 32, 128 / 32), 256, 0, stream>>>(
      Ws, WsT, 128, 256);

  // One wave per node: 4 waves per block.
  scatter_node_seg<<<(M + 3) / 4, 256, 0, stream>>>(
      node_features, node_senders, node_conv, ro1, Ab, c1, M);
  scatter_hedge_seg<<<(M + 3) / 4, 256, 0, stream>>>(
      hedge_features, h2n_senders, h2n_conv, ro2, Bb, c2, M);

  gemm_combine_mfma<<<Mp / 64, 512, 0, stream>>>(
      Ab, Bb, c1, c2, WmT, bm, WsT, bs, out, M);
}

// Round 4
// 176.801 us; speedup vs baseline: 2.8516x; 1.2745x over previous
//
#include <hip/hip_runtime.h>

// ---------------------------------------------------------------------------
// Pipeline (algebraically restructured from the reference):
//   Xb = bf16(node_features), Hb = bf16(hedge_features)     (one streaming pass)
//   A[n,:]  = sum_{e: rcv=n} conv_e * Xb[snd_e,:]           (f32 acc -> bf16)
//   c1[n]   = sum_{e: rcv=n} conv_e
//   B[n,:]  = sum_{e2} conv2_e * Hb[snd_e,:]                (f32 acc -> bf16)
//   c2[n]   = sum conv2_e
//   out     = (A@Wm + c1*bm) .* (B@Ws + c2*bs)   -- bf16 MFMA, f32 accum
// ---------------------------------------------------------------------------

typedef __attribute__((ext_vector_type(8))) short bf16x8;
typedef __attribute__((ext_vector_type(4))) float f32x4;

static __device__ __forceinline__ unsigned short f2bf(float f) {
  unsigned u = __float_as_uint(f);
  u += 0x7fff + ((u >> 16) & 1);          // round-to-nearest-even
  return (unsigned short)(u >> 16);
}
static __device__ __forceinline__ float bf2f(unsigned short h) {
  return __uint_as_float((unsigned)h << 16);
}

// f32 -> bf16 streaming convert, float4 in / ushort4 out per thread.
__global__ __launch_bounds__(256) void cvt_bf16(
    const float* __restrict__ src, unsigned short* __restrict__ dst, int n4)
{
  const int i = blockIdx.x * blockDim.x + threadIdx.x;
  if (i >= n4) return;
  const float4 v = reinterpret_cast<const float4*>(src)[i];
  reinterpret_cast<ushort4*>(dst)[i] =
      make_ushort4(f2bf(v.x), f2bf(v.y), f2bf(v.z), f2bf(v.w));
}

// row_start[n] = first edge index e with rcv[e] >= n  (n in [0, N]).
__global__ __launch_bounds__(256) void build_row_offsets(
    const int* __restrict__ rcv, int E, int N, int* __restrict__ row_start)
{
  const int e = blockIdx.x * blockDim.x + threadIdx.x;
  if (e >= E) return;
  const int c = rcv[e];
  const int p = (e == 0) ? -1 : rcv[e - 1];
  for (int n = p + 1; n <= c; ++n) row_start[n] = e;
  if (e == E - 1) {
    for (int n = c + 1; n <= N; ++n) row_start[n] = E;
  }
}

// W[K][N] f32 -> WT[N][K] bf16 via LDS 32x32 tile transpose.
__global__ __launch_bounds__(256) void transpose_to_bf16(
    const float* __restrict__ W, unsigned short* __restrict__ WT, int K, int N)
{
  __shared__ float t[32][33];
  const int tx = threadIdx.x & 31, ty = threadIdx.x >> 5;   // 32 x 8
  const int n0 = blockIdx.x * 32, k0 = blockIdx.y * 32;
#pragma unroll
  for (int i = 0; i < 32; i += 8)
    t[ty + i][tx] = W[(size_t)(k0 + ty + i) * N + n0 + tx];
  __syncthreads();
#pragma unroll
  for (int i = 0; i < 32; i += 8)
    WT[(size_t)(n0 + ty + i) * K + k0 + tx] = f2bf(t[tx][ty + i]);
}

// One wave per node, C=256 bf16 channels (ushort4 per lane). No atomics.
__global__ __launch_bounds__(256) void scatter_node_seg(
    const unsigned short* __restrict__ X,   // [Nsrc,256] bf16
    const int* __restrict__ snd,
    const float* __restrict__ conv,
    const int* __restrict__ row_start,      // [N+1]
    unsigned short* __restrict__ A,         // [Mp,256] bf16
    float* __restrict__ csum,               // [Mp]
    int N)
{
  const int lane = threadIdx.x & 63;
  const int node = __builtin_amdgcn_readfirstlane(
      (int)blockIdx.x * 4 + ((int)threadIdx.x >> 6));
  if (node >= N) return;
  const int lo = row_start[node];
  const int hi = row_start[node + 1];

  const unsigned short* Xl = X + lane * 4;
  float4 acc = make_float4(0.f, 0.f, 0.f, 0.f);
  float cacc = 0.f;

  int e = lo;
  for (; e + 8 <= hi; e += 8) {
    int s[8]; float cv[8]; ushort4 x[8];
#pragma unroll
    for (int j = 0; j < 8; ++j) s[j] = snd[e + j];
#pragma unroll
    for (int j = 0; j < 8; ++j) cv[j] = conv[e + j];
#pragma unroll
    for (int j = 0; j < 8; ++j)
      x[j] = *reinterpret_cast<const ushort4*>(Xl + (size_t)s[j] * 256);
#pragma unroll
    for (int j = 0; j < 8; ++j) {
      acc.x = fmaf(cv[j], bf2f(x[j].x), acc.x);
      acc.y = fmaf(cv[j], bf2f(x[j].y), acc.y);
      acc.z = fmaf(cv[j], bf2f(x[j].z), acc.z);
      acc.w = fmaf(cv[j], bf2f(x[j].w), acc.w);
      cacc += cv[j];
    }
  }
  for (; e < hi; ++e) {
    const int s = snd[e];
    const float cv = conv[e];
    const ushort4 x = *reinterpret_cast<const ushort4*>(Xl + (size_t)s * 256);
    acc.x = fmaf(cv, bf2f(x.x), acc.x);
    acc.y = fmaf(cv, bf2f(x.y), acc.y);
    acc.z = fmaf(cv, bf2f(x.z), acc.z);
    acc.w = fmaf(cv, bf2f(x.w), acc.w);
    cacc += cv;
  }

  *reinterpret_cast<ushort4*>(A + (size_t)node * 256 + lane * 4) =
      make_ushort4(f2bf(acc.x), f2bf(acc.y), f2bf(acc.z), f2bf(acc.w));
  if (lane == 0) csum[node] = cacc;
}

// One wave per node, C=128 bf16 channels (ushort2 per lane). No atomics.
__global__ __launch_bounds__(256) void scatter_hedge_seg(
    const unsigned short* __restrict__ X,   // [Nsrc,128] bf16
    const int* __restrict__ snd,
    const float* __restrict__ conv,
    const int* __restrict__ row_start,      // [N+1]
    unsigned short* __restrict__ B,         // [Mp,128] bf16
    float* __restrict__ csum,               // [Mp]
    int N)
{
  const int lane = threadIdx.x & 63;
  const int node = __builtin_amdgcn_readfirstlane(
      (int)blockIdx.x * 4 + ((int)threadIdx.x >> 6));
  if (node >= N) return;
  const int lo = row_start[node];
  const int hi = row_start[node + 1];

  const unsigned short* Xl = X + lane * 2;
  float2 acc = make_float2(0.f, 0.f);
  float cacc = 0.f;

  int e = lo;
  for (; e + 8 <= hi; e += 8) {
    int s[8]; float cv[8]; ushort2 x[8];
#pragma unroll
    for (int j = 0; j < 8; ++j) s[j] = snd[e + j];
#pragma unroll
    for (int j = 0; j < 8; ++j) cv[j] = conv[e + j];
#pragma unroll
    for (int j = 0; j < 8; ++j)
      x[j] = *reinterpret_cast<const ushort2*>(Xl + (size_t)s[j] * 128);
#pragma unroll
    for (int j = 0; j < 8; ++j) {
      acc.x = fmaf(cv[j], bf2f(x[j].x), acc.x);
      acc.y = fmaf(cv[j], bf2f(x[j].y), acc.y);
      cacc += cv[j];
    }
  }
  for (; e < hi; ++e) {
    const int s = snd[e];
    const float cv = conv[e];
    const ushort2 x = *reinterpret_cast<const ushort2*>(Xl + (size_t)s * 128);
    acc.x = fmaf(cv, bf2f(x.x), acc.x);
    acc.y = fmaf(cv, bf2f(x.y), acc.y);
    cacc += cv;
  }

  *reinterpret_cast<ushort2*>(B + (size_t)node * 128 + lane * 2) =
      make_ushort2(f2bf(acc.x), f2bf(acc.y));
  if (lane == 0) csum[node] = cacc;
}

// MFMA dual-GEMM + bias + Hadamard. Block = 512 threads = 8 waves (2m x 4n).
// Block tile 64 rows x 256 cols; wave tile 32 rows x 64 cols.
// mfma_f32_16x16x32_bf16 fragments:
//   A-frag: row = lane&15, k = 8*(lane>>4) + j
//   B-frag: col = lane&15, k = 8*(lane>>4) + j
//   C/D   : col = lane&15, row = 4*(lane>>4) + reg   [m89-verified]
__global__ __launch_bounds__(512) void gemm_combine_mfma(
    const unsigned short* __restrict__ A,    // [Mp,256] bf16
    const unsigned short* __restrict__ B,    // [Mp,128] bf16
    const float* __restrict__ c1,            // [Mp]
    const float* __restrict__ c2,            // [Mp]
    const unsigned short* __restrict__ WmT,  // [256,256] bf16 (N-major)
    const float* __restrict__ bm,            // [256]
    const unsigned short* __restrict__ WsT,  // [256,128] bf16 (N-major)
    const float* __restrict__ bs,            // [256]
    float* __restrict__ out,                 // [M,256]
    int M)
{
  const int lane = threadIdx.x & 63;
  const int wv = threadIdx.x >> 6;
  const int wvm = wv >> 2;            // 0..1
  const int wvn = wv & 3;             // 0..3
  const int l15 = lane & 15;
  const int lg  = lane >> 4;          // 0..3
  const int m0 = blockIdx.x * 64;

  const int rowA = m0 + wvm * 32 + l15;     // + ms*16
  const int colW = wvn * 64 + l15;          // + n*16

  f32x4 accM[2][4];
  f32x4 accS[2][4];
#pragma unroll
  for (int ms = 0; ms < 2; ++ms)
#pragma unroll
    for (int n = 0; n < 4; ++n) {
      accM[ms][n] = (f32x4)0.f;
      accS[ms][n] = (f32x4)0.f;
    }

  // ---- accM = A @ Wm, K = 256 ----
#pragma unroll
  for (int kc = 0; kc < 256; kc += 32) {
    const int ko = kc + lg * 8;
    const bf16x8 a0 = *reinterpret_cast<const bf16x8*>(A + (size_t)rowA * 256 + ko);
    const bf16x8 a1 = *reinterpret_cast<const bf16x8*>(A + (size_t)(rowA + 16) * 256 + ko);
#pragma unroll
    for (int n = 0; n < 4; ++n) {
      const bf16x8 w = *reinterpret_cast<const bf16x8*>(
          WmT + (size_t)(colW + n * 16) * 256 + ko);
      accM[0][n] = __builtin_amdgcn_mfma_f32_16x16x32_bf16(a0, w, accM[0][n], 0, 0, 0);
      accM[1][n] = __builtin_amdgcn_mfma_f32_16x16x32_bf16(a1, w, accM[1][n], 0, 0, 0);
    }
  }

  // ---- accS = B @ Ws, K = 128 ----
#pragma unroll
  for (int kc = 0; kc < 128; kc += 32) {
    const int ko = kc + lg * 8;
    const bf16x8 b0 = *reinterpret_cast<const bf16x8*>(B + (size_t)rowA * 128 + ko);
    const bf16x8 b1 = *reinterpret_cast<const bf16x8*>(B + (size_t)(rowA + 16) * 128 + ko);
#pragma unroll
    for (int n = 0; n < 4; ++n) {
      const bf16x8 w = *reinterpret_cast<const bf16x8*>(
          WsT + (size_t)(colW + n * 16) * 128 + ko);
      accS[0][n] = __builtin_amdgcn_mfma_f32_16x16x32_bf16(b0, w, accS[0][n], 0, 0, 0);
      accS[1][n] = __builtin_amdgcn_mfma_f32_16x16x32_bf16(b1, w, accS[1][n], 0, 0, 0);
    }
  }

  // ---- epilogue: (accM + c1*bm) .* (accS + c2*bs) ----
  float bmv[4], bsv[4];
#pragma unroll
  for (int n = 0; n < 4; ++n) {
    bmv[n] = bm[colW + n * 16];
    bsv[n] = bs[colW + n * 16];
  }
#pragma unroll
  for (int ms = 0; ms < 2; ++ms) {
    const int rbase = m0 + wvm * 32 + ms * 16 + lg * 4;
#pragma unroll
    for (int r = 0; r < 4; ++r) {
      const int row = rbase + r;
      if (row < M) {
        const float k1 = c1[row];
        const float k2 = c2[row];
#pragma unroll
        for (int n = 0; n < 4; ++n) {
          const int col = colW + n * 16;
          const float mv = accM[ms][n][r] + k1 * bmv[n];
          const float sv = accS[ms][n][r] + k2 * bsv[n];
          out[(size_t)row * 256 + col] = mv * sv;
        }
      }
    }
  }
}

extern "C" void kernel_launch(void* const* d_in, const int* in_sizes, int n_in,
                              void* d_out, int out_size, void* d_ws, size_t ws_size,
                              hipStream_t stream) {
  const float* node_features  = (const float*)d_in[0];   // [50000,256]
  const float* hedge_features = (const float*)d_in[1];   // [25000,128]
  const int*   node_senders   = (const int*)d_in[2];     // [E]
  const int*   node_receivers = (const int*)d_in[3];     // [E] sorted
  const float* node_conv      = (const float*)d_in[4];   // [E]
  const int*   h2n_senders    = (const int*)d_in[5];     // [E2]
  const int*   h2n_receivers  = (const int*)d_in[6];     // [E2] sorted
  const float* h2n_conv       = (const float*)d_in[7];   // [E2]
  const float* Wm             = (const float*)d_in[8];   // [256,256]
  const float* bm             = (const float*)d_in[9];   // [256]
  const float* Ws             = (const float*)d_in[10];  // [128,256]
  const float* bs             = (const float*)d_in[11];  // [256]
  float* out = (float*)d_out;

  const int M   = in_sizes[0] / 256;       // 50000 nodes
  const int Nh  = in_sizes[1] / 128;       // 25000 hedges
  const int E   = in_sizes[2];             // 800000
  const int E2  = in_sizes[5];             // 400000
  const int Mp  = ((M + 63) / 64) * 64;    // padded rows for GEMM tiles

  // Workspace layout (bf16 = unsigned short):
  //   A[Mp,256] | B[Mp,128] | Xb[M,256] | Hb[Nh,128] | WmT[256,256] | WsT[256,128]
  //   | c1 f32 [Mp] | c2 f32 [Mp] | ro1 [M+1] | ro2 [M+1]
  unsigned short* Ab  = (unsigned short*)d_ws;
  unsigned short* Bb  = Ab + (size_t)Mp * 256;
  unsigned short* Xb  = Bb + (size_t)Mp * 128;
  unsigned short* Hb  = Xb + (size_t)M * 256;
  unsigned short* WmT = Hb + (size_t)Nh * 128;
  unsigned short* WsT = WmT + 256 * 256;
  float* c1 = (float*)(WsT + 256 * 128);
  float* c2 = c1 + Mp;
  int*   ro1 = (int*)(c2 + Mp);
  int*   ro2 = ro1 + (M + 1);

  // Pre-convert feature tables to bf16 (halves gather traffic).
  const int nx4 = M * 256 / 4, nh4 = Nh * 128 / 4;
  cvt_bf16<<<(nx4 + 255) / 256, 256, 0, stream>>>(node_features, Xb, nx4);
  cvt_bf16<<<(nh4 + 255) / 256, 256, 0, stream>>>(hedge_features, Hb, nh4);

  build_row_offsets<<<(E + 255) / 256, 256, 0, stream>>>(
      node_receivers, E, M, ro1);
  build_row_offsets<<<(E2 + 255) / 256, 256, 0, stream>>>(
      h2n_receivers, E2, M, ro2);

  transpose_to_bf16<<<dim3(256 / 32, 256 / 32), 256, 0, stream>>>(
      Wm, WmT, 256, 256);
  transpose_to_bf16<<<dim3(256 / 32, 128 / 32), 256, 0, stream>>>(
      Ws, WsT, 128, 256);

  // One wave per node: 4 waves per block.
  scatter_node_seg<<<(M + 3) / 4, 256, 0, stream>>>(
      Xb, node_senders, node_conv, ro1, Ab, c1, M);
  scatter_hedge_seg<<<(M + 3) / 4, 256, 0, stream>>>(
      Hb, h2n_senders, h2n_conv, ro2, Bb, c2, M);

  gemm_combine_mfma<<<Mp / 64, 512, 0, stream>>>(
      Ab, Bb, c1, c2, WmT, bm, WsT, bs, out, M);
}

// Round 5
// 144.998 us; speedup vs baseline: 3.4771x; 1.2193x over previous
//
#include <hip/hip_runtime.h>

// ---------------------------------------------------------------------------
// Pipeline (algebraically restructured from the reference):
//   Xb = bf16(node_features), Hb = bf16(hedge_features)     (one streaming pass)
//   A[n,:]  = sum_{e: rcv=n} conv_e * Xb[snd_e,:]           (f32 acc -> bf16)
//   c1[n]   = sum_{e: rcv=n} conv_e
//   B[n,:]  = sum_{e2} conv2_e * Hb[snd_e,:]                (f32 acc -> bf16)
//   c2[n]   = sum conv2_e
//   out     = (A@Wm + c1*bm) .* (B@Ws + c2*bs)   -- bf16 MFMA, f32 accum
// ---------------------------------------------------------------------------

typedef __attribute__((ext_vector_type(8))) short bf16x8;
typedef __attribute__((ext_vector_type(4))) float f32x4;

static __device__ __forceinline__ unsigned short f2bf(float f) {
  unsigned u = __float_as_uint(f);
  u += 0x7fff + ((u >> 16) & 1);          // round-to-nearest-even
  return (unsigned short)(u >> 16);
}
static __device__ __forceinline__ float bf2f(unsigned short h) {
  return __uint_as_float((unsigned)h << 16);
}

// f32 -> bf16 streaming convert, float4 in / ushort4 out per thread.
__global__ __launch_bounds__(256) void cvt_bf16(
    const float* __restrict__ src, unsigned short* __restrict__ dst, int n4)
{
  const int i = blockIdx.x * blockDim.x + threadIdx.x;
  if (i >= n4) return;
  const float4 v = reinterpret_cast<const float4*>(src)[i];
  reinterpret_cast<ushort4*>(dst)[i] =
      make_ushort4(f2bf(v.x), f2bf(v.y), f2bf(v.z), f2bf(v.w));
}

// row_start[n] = first edge index e with rcv[e] >= n  (n in [0, N]).
__global__ __launch_bounds__(256) void build_row_offsets(
    const int* __restrict__ rcv, int E, int N, int* __restrict__ row_start)
{
  const int e = blockIdx.x * blockDim.x + threadIdx.x;
  if (e >= E) return;
  const int c = rcv[e];
  const int p = (e == 0) ? -1 : rcv[e - 1];
  for (int n = p + 1; n <= c; ++n) row_start[n] = e;
  if (e == E - 1) {
    for (int n = c + 1; n <= N; ++n) row_start[n] = E;
  }
}

// W[K][N] f32 -> WT[N][K] bf16 via LDS 32x32 tile transpose.
__global__ __launch_bounds__(256) void transpose_to_bf16(
    const float* __restrict__ W, unsigned short* __restrict__ WT, int K, int N)
{
  __shared__ float t[32][33];
  const int tx = threadIdx.x & 31, ty = threadIdx.x >> 5;   // 32 x 8
  const int n0 = blockIdx.x * 32, k0 = blockIdx.y * 32;
#pragma unroll
  for (int i = 0; i < 32; i += 8)
    t[ty + i][tx] = W[(size_t)(k0 + ty + i) * N + n0 + tx];
  __syncthreads();
#pragma unroll
  for (int i = 0; i < 32; i += 8)
    WT[(size_t)(n0 + ty + i) * K + k0 + tx] = f2bf(t[tx][ty + i]);
}

// One wave per node, C=256 bf16 channels (ushort4 per lane). No atomics.
__global__ __launch_bounds__(256) void scatter_node_seg(
    const unsigned short* __restrict__ X,   // [Nsrc,256] bf16
    const int* __restrict__ snd,
    const float* __restrict__ conv,
    const int* __restrict__ row_start,      // [N+1]
    unsigned short* __restrict__ A,         // [Mp,256] bf16
    float* __restrict__ csum,               // [Mp]
    int N)
{
  const int lane = threadIdx.x & 63;
  const int node = __builtin_amdgcn_readfirstlane(
      (int)blockIdx.x * 4 + ((int)threadIdx.x >> 6));
  if (node >= N) return;
  const int lo = row_start[node];
  const int hi = row_start[node + 1];

  const unsigned short* Xl = X + lane * 4;
  float4 acc = make_float4(0.f, 0.f, 0.f, 0.f);
  float cacc = 0.f;

  int e = lo;
  for (; e + 8 <= hi; e += 8) {
    int s[8]; float cv[8]; ushort4 x[8];
#pragma unroll
    for (int j = 0; j < 8; ++j) s[j] = snd[e + j];
#pragma unroll
    for (int j = 0; j < 8; ++j) cv[j] = conv[e + j];
#pragma unroll
    for (int j = 0; j < 8; ++j)
      x[j] = *reinterpret_cast<const ushort4*>(Xl + (size_t)s[j] * 256);
#pragma unroll
    for (int j = 0; j < 8; ++j) {
      acc.x = fmaf(cv[j], bf2f(x[j].x), acc.x);
      acc.y = fmaf(cv[j], bf2f(x[j].y), acc.y);
      acc.z = fmaf(cv[j], bf2f(x[j].z), acc.z);
      acc.w = fmaf(cv[j], bf2f(x[j].w), acc.w);
      cacc += cv[j];
    }
  }
  for (; e < hi; ++e) {
    const int s = snd[e];
    const float cv = conv[e];
    const ushort4 x = *reinterpret_cast<const ushort4*>(Xl + (size_t)s * 256);
    acc.x = fmaf(cv, bf2f(x.x), acc.x);
    acc.y = fmaf(cv, bf2f(x.y), acc.y);
    acc.z = fmaf(cv, bf2f(x.z), acc.z);
    acc.w = fmaf(cv, bf2f(x.w), acc.w);
    cacc += cv;
  }

  *reinterpret_cast<ushort4*>(A + (size_t)node * 256 + lane * 4) =
      make_ushort4(f2bf(acc.x), f2bf(acc.y), f2bf(acc.z), f2bf(acc.w));
  if (lane == 0) csum[node] = cacc;
}

// One wave per node, C=128 bf16 channels (ushort2 per lane). No atomics.
__global__ __launch_bounds__(256) void scatter_hedge_seg(
    const unsigned short* __restrict__ X,   // [Nsrc,128] bf16
    const int* __restrict__ snd,
    const float* __restrict__ conv,
    const int* __restrict__ row_start,      // [N+1]
    unsigned short* __restrict__ B,         // [Mp,128] bf16
    float* __restrict__ csum,               // [Mp]
    int N)
{
  const int lane = threadIdx.x & 63;
  const int node = __builtin_amdgcn_readfirstlane(
      (int)blockIdx.x * 4 + ((int)threadIdx.x >> 6));
  if (node >= N) return;
  const int lo = row_start[node];
  const int hi = row_start[node + 1];

  const unsigned short* Xl = X + lane * 2;
  float2 acc = make_float2(0.f, 0.f);
  float cacc = 0.f;

  int e = lo;
  for (; e + 8 <= hi; e += 8) {
    int s[8]; float cv[8]; ushort2 x[8];
#pragma unroll
    for (int j = 0; j < 8; ++j) s[j] = snd[e + j];
#pragma unroll
    for (int j = 0; j < 8; ++j) cv[j] = conv[e + j];
#pragma unroll
    for (int j = 0; j < 8; ++j)
      x[j] = *reinterpret_cast<const ushort2*>(Xl + (size_t)s[j] * 128);
#pragma unroll
    for (int j = 0; j < 8; ++j) {
      acc.x = fmaf(cv[j], bf2f(x[j].x), acc.x);
      acc.y = fmaf(cv[j], bf2f(x[j].y), acc.y);
      cacc += cv[j];
    }
  }
  for (; e < hi; ++e) {
    const int s = snd[e];
    const float cv = conv[e];
    const ushort2 x = *reinterpret_cast<const ushort2*>(Xl + (size_t)s * 128);
    acc.x = fmaf(cv, bf2f(x.x), acc.x);
    acc.y = fmaf(cv, bf2f(x.y), acc.y);
    cacc += cv;
  }

  *reinterpret_cast<ushort2*>(B + (size_t)node * 128 + lane * 2) =
      make_ushort2(f2bf(acc.x), f2bf(acc.y));
  if (lane == 0) csum[node] = cacc;
}

// MFMA dual-GEMM + bias + Hadamard, LDS-cached weight slice.
// Grid: (Mp/256, 4). Block = 512 threads = 8 waves; block tile 256 rows x
// 64 cols. Each wave owns 32 rows x 64 cols (2 m-sub x 4 n-sub of 16x16).
// W slice staged in LDS once per block (row stride padded: 2-way bank
// aliasing only, free). A/B rows stream from L3.
// mfma_f32_16x16x32_bf16 fragments:
//   A-frag: row = lane&15, k = 8*(lane>>4) + j
//   B-frag: col = lane&15, k = 8*(lane>>4) + j
//   C/D   : col = lane&15, row = 4*(lane>>4) + reg   [m89-verified]
__global__ __launch_bounds__(512) void gemm_combine_mfma(
    const unsigned short* __restrict__ A,    // [Mp,256] bf16
    const unsigned short* __restrict__ B,    // [Mp,128] bf16
    const float* __restrict__ c1,            // [Mp]
    const float* __restrict__ c2,            // [Mp]
    const unsigned short* __restrict__ WmT,  // [256,256] bf16 (N-major)
    const float* __restrict__ bm,            // [256]
    const unsigned short* __restrict__ WsT,  // [256,128] bf16 (N-major)
    const float* __restrict__ bs,            // [256]
    float* __restrict__ out,                 // [M,256]
    int M)
{
  __shared__ unsigned short lWm[64][264];    // 64 cols x 256 K, +8 pad
  __shared__ unsigned short lWs[64][136];    // 64 cols x 128 K, +8 pad

  const int tid  = (int)threadIdx.x;
  const int lane = tid & 63;
  const int wv   = tid >> 6;          // 0..7
  const int l15  = lane & 15;
  const int lg   = lane >> 4;         // 0..3
  const int m0      = blockIdx.x * 256;
  const int colBlk  = blockIdx.y * 64;

  // ---- stage weight slices into LDS ----
  for (int i = tid; i < 64 * 256 / 8; i += 512) {       // 2048 x 16B
    const int c = i >> 5, k8 = (i & 31) << 3;
    *reinterpret_cast<bf16x8*>(&lWm[c][k8]) =
        *reinterpret_cast<const bf16x8*>(WmT + (size_t)(colBlk + c) * 256 + k8);
  }
  for (int i = tid; i < 64 * 128 / 8; i += 512) {       // 1024 x 16B
    const int c = i >> 4, k8 = (i & 15) << 3;
    *reinterpret_cast<bf16x8*>(&lWs[c][k8]) =
        *reinterpret_cast<const bf16x8*>(WsT + (size_t)(colBlk + c) * 128 + k8);
  }
  __syncthreads();

  const int rowA = m0 + wv * 32 + l15;

  f32x4 accM[2][4];
  f32x4 accS[2][4];
#pragma unroll
  for (int ms = 0; ms < 2; ++ms)
#pragma unroll
    for (int n = 0; n < 4; ++n) {
      accM[ms][n] = (f32x4)0.f;
      accS[ms][n] = (f32x4)0.f;
    }

  // ---- accM = A @ Wm, K = 256 ----
#pragma unroll
  for (int kc = 0; kc < 256; kc += 32) {
    const int ko = kc + lg * 8;
    const bf16x8 a0 = *reinterpret_cast<const bf16x8*>(A + (size_t)rowA * 256 + ko);
    const bf16x8 a1 = *reinterpret_cast<const bf16x8*>(A + (size_t)(rowA + 16) * 256 + ko);
#pragma unroll
    for (int n = 0; n < 4; ++n) {
      const bf16x8 w = *reinterpret_cast<const bf16x8*>(&lWm[l15 + n * 16][ko]);
      accM[0][n] = __builtin_amdgcn_mfma_f32_16x16x32_bf16(a0, w, accM[0][n], 0, 0, 0);
      accM[1][n] = __builtin_amdgcn_mfma_f32_16x16x32_bf16(a1, w, accM[1][n], 0, 0, 0);
    }
  }

  // ---- accS = B @ Ws, K = 128 ----
#pragma unroll
  for (int kc = 0; kc < 128; kc += 32) {
    const int ko = kc + lg * 8;
    const bf16x8 b0 = *reinterpret_cast<const bf16x8*>(B + (size_t)rowA * 128 + ko);
    const bf16x8 b1 = *reinterpret_cast<const bf16x8*>(B + (size_t)(rowA + 16) * 128 + ko);
#pragma unroll
    for (int n = 0; n < 4; ++n) {
      const bf16x8 w = *reinterpret_cast<const bf16x8*>(&lWs[l15 + n * 16][ko]);
      accS[0][n] = __builtin_amdgcn_mfma_f32_16x16x32_bf16(b0, w, accS[0][n], 0, 0, 0);
      accS[1][n] = __builtin_amdgcn_mfma_f32_16x16x32_bf16(b1, w, accS[1][n], 0, 0, 0);
    }
  }

  // ---- epilogue: (accM + c1*bm) .* (accS + c2*bs) ----
  float bmv[4], bsv[4];
#pragma unroll
  for (int n = 0; n < 4; ++n) {
    bmv[n] = bm[colBlk + n * 16 + l15];
    bsv[n] = bs[colBlk + n * 16 + l15];
  }
#pragma unroll
  for (int ms = 0; ms < 2; ++ms) {
    const int rbase = m0 + wv * 32 + ms * 16 + lg * 4;
#pragma unroll
    for (int r = 0; r < 4; ++r) {
      const int row = rbase + r;
      if (row < M) {
        const float k1 = c1[row];
        const float k2 = c2[row];
#pragma unroll
        for (int n = 0; n < 4; ++n) {
          const int col = colBlk + n * 16 + l15;
          const float mv = accM[ms][n][r] + k1 * bmv[n];
          const float sv = accS[ms][n][r] + k2 * bsv[n];
          out[(size_t)row * 256 + col] = mv * sv;
        }
      }
    }
  }
}

extern "C" void kernel_launch(void* const* d_in, const int* in_sizes, int n_in,
                              void* d_out, int out_size, void* d_ws, size_t ws_size,
                              hipStream_t stream) {
  const float* node_features  = (const float*)d_in[0];   // [50000,256]
  const float* hedge_features = (const float*)d_in[1];   // [25000,128]
  const int*   node_senders   = (const int*)d_in[2];     // [E]
  const int*   node_receivers = (const int*)d_in[3];     // [E] sorted
  const float* node_conv      = (const float*)d_in[4];   // [E]
  const int*   h2n_senders    = (const int*)d_in[5];     // [E2]
  const int*   h2n_receivers  = (const int*)d_in[6];     // [E2] sorted
  const float* h2n_conv       = (const float*)d_in[7];   // [E2]
  const float* Wm             = (const float*)d_in[8];   // [256,256]
  const float* bm             = (const float*)d_in[9];   // [256]
  const float* Ws             = (const float*)d_in[10];  // [128,256]
  const float* bs             = (const float*)d_in[11];  // [256]
  float* out = (float*)d_out;

  const int M   = in_sizes[0] / 256;       // 50000 nodes
  const int Nh  = in_sizes[1] / 128;       // 25000 hedges
  const int E   = in_sizes[2];             // 800000
  const int E2  = in_sizes[5];             // 400000
  const int Mp  = ((M + 255) / 256) * 256; // padded rows for 256-row GEMM tiles

  // Workspace layout (bf16 = unsigned short):
  //   A[Mp,256] | B[Mp,128] | Xb[M,256] | Hb[Nh,128] | WmT[256,256] | WsT[256,128]
  //   | c1 f32 [Mp] | c2 f32 [Mp] | ro1 [M+1] | ro2 [M+1]
  unsigned short* Ab  = (unsigned short*)d_ws;
  unsigned short* Bb  = Ab + (size_t)Mp * 256;
  unsigned short* Xb  = Bb + (size_t)Mp * 128;
  unsigned short* Hb  = Xb + (size_t)M * 256;
  unsigned short* WmT = Hb + (size_t)Nh * 128;
  unsigned short* WsT = WmT + 256 * 256;
  float* c1 = (float*)(WsT + 256 * 128);
  float* c2 = c1 + Mp;
  int*   ro1 = (int*)(c2 + Mp);
  int*   ro2 = ro1 + (M + 1);

  // Pre-convert feature tables to bf16 (halves gather traffic).
  const int nx4 = M * 256 / 4, nh4 = Nh * 128 / 4;
  cvt_bf16<<<(nx4 + 255) / 256, 256, 0, stream>>>(node_features, Xb, nx4);
  cvt_bf16<<<(nh4 + 255) / 256, 256, 0, stream>>>(hedge_features, Hb, nh4);

  build_row_offsets<<<(E + 255) / 256, 256, 0, stream>>>(
      node_receivers, E, M, ro1);
  build_row_offsets<<<(E2 + 255) / 256, 256, 0, stream>>>(
      h2n_receivers, E2, M, ro2);

  transpose_to_bf16<<<dim3(256 / 32, 256 / 32), 256, 0, stream>>>(
      Wm, WmT, 256, 256);
  transpose_to_bf16<<<dim3(256 / 32, 128 / 32), 256, 0, stream>>>(
      Ws, WsT, 128, 256);

  // One wave per node: 4 waves per block.
  scatter_node_seg<<<(M + 3) / 4, 256, 0, stream>>>(
      Xb, node_senders, node_conv, ro1, Ab, c1, M);
  scatter_hedge_seg<<<(M + 3) / 4, 256, 0, stream>>>(
      Hb, h2n_senders, h2n_conv, ro2, Bb, c2, M);

  gemm_combine_mfma<<<dim3(Mp / 256, 4), 512, 0, stream>>>(
      Ab, Bb, c1, c2, WmT, bm, WsT, bs, out, M);
}

// Round 6
// 134.292 us; speedup vs baseline: 3.7543x; 1.0797x over previous
//
#include <hip/hip_runtime.h>

// ---------------------------------------------------------------------------
// Pipeline (algebraically restructured from the reference):
//   Xb = bf16(node_features), Hb = bf16(hedge_features)
//   A[n,:]  = sum_{e: rcv=n} conv_e * Xb[snd_e,:]           (f32 acc -> bf16)
//   c1[n]   = sum_{e: rcv=n} conv_e
//   B[n,:]  = sum_{e2} conv2_e * Hb[snd_e,:]                (f32 acc -> bf16)
//   c2[n]   = sum conv2_e
//   out     = (A@Wm + c1*bm) .* (B@Ws + c2*bs)   -- bf16 MFMA, f32 accum
//
// 3 dispatches: prep_all (cvt+rowoff+transpose fused) -> scatter_fused
// (node blocks first, hedge blocks fill behind) -> gemm_combine_mfma.
// ---------------------------------------------------------------------------

typedef __attribute__((ext_vector_type(8))) short bf16x8;
typedef __attribute__((ext_vector_type(4))) float f32x4;

static __device__ __forceinline__ unsigned short f2bf(float f) {
  unsigned u = __float_as_uint(f);
  u += 0x7fff + ((u >> 16) & 1);          // round-to-nearest-even
  return (unsigned short)(u >> 16);
}
static __device__ __forceinline__ float bf2f(unsigned short h) {
  return __uint_as_float((unsigned)h << 16);
}

// ---------------------------------------------------------------------------
// prep_all: blockIdx ranges ->
//   [0,bX)           : cvt X f32->bf16 (float4/lane)
//   [bX,bX+bH)       : cvt H f32->bf16
//   [..,+bE1)        : row offsets for node_receivers
//   [..,+bE2)        : row offsets for h2n_receivers
//   [..,+64)         : transpose Wm (256x256) -> WmT bf16
//   [..,+32)         : transpose Ws (128x256) -> WsT bf16
// ---------------------------------------------------------------------------
__global__ __launch_bounds__(256) void prep_all(
    const float* __restrict__ X, const float* __restrict__ H,
    const int* __restrict__ rcv1, int E1,
    const int* __restrict__ rcv2, int E2, int N,
    const float* __restrict__ Wm, const float* __restrict__ Ws,
    unsigned short* __restrict__ Xb, unsigned short* __restrict__ Hb,
    int* __restrict__ ro1, int* __restrict__ ro2,
    unsigned short* __restrict__ WmT, unsigned short* __restrict__ WsT,
    int nX4, int nH4)
{
  __shared__ float t[32][33];
  const int tid = (int)threadIdx.x;
  int b = (int)blockIdx.x;

  const int bX  = (nX4 + 255) / 256;
  const int bH  = (nH4 + 255) / 256;
  const int bE1 = (E1 + 255) / 256;
  const int bE2 = (E2 + 255) / 256;

  if (b < bX) {                       // ---- cvt X ----
    const int i = b * 256 + tid;
    if (i < nX4) {
      const float4 v = reinterpret_cast<const float4*>(X)[i];
      reinterpret_cast<ushort4*>(Xb)[i] =
          make_ushort4(f2bf(v.x), f2bf(v.y), f2bf(v.z), f2bf(v.w));
    }
    return;
  }
  b -= bX;
  if (b < bH) {                       // ---- cvt H ----
    const int i = b * 256 + tid;
    if (i < nH4) {
      const float4 v = reinterpret_cast<const float4*>(H)[i];
      reinterpret_cast<ushort4*>(Hb)[i] =
          make_ushort4(f2bf(v.x), f2bf(v.y), f2bf(v.z), f2bf(v.w));
    }
    return;
  }
  b -= bH;
  if (b < bE1) {                      // ---- row offsets 1 ----
    const int e = b * 256 + tid;
    if (e < E1) {
      const int c = rcv1[e];
      const int p = (e == 0) ? -1 : rcv1[e - 1];
      for (int n = p + 1; n <= c; ++n) ro1[n] = e;
      if (e == E1 - 1)
        for (int n = c + 1; n <= N; ++n) ro1[n] = E1;
    }
    return;
  }
  b -= bE1;
  if (b < bE2) {                      // ---- row offsets 2 ----
    const int e = b * 256 + tid;
    if (e < E2) {
      const int c = rcv2[e];
      const int p = (e == 0) ? -1 : rcv2[e - 1];
      for (int n = p + 1; n <= c; ++n) ro2[n] = e;
      if (e == E2 - 1)
        for (int n = c + 1; n <= N; ++n) ro2[n] = E2;
    }
    return;
  }
  b -= bE2;
  {
    // ---- weight transposes: Wm tiles [0,64), Ws tiles [64,96) ----
    const float* W; unsigned short* WT; int K, Nn, tile;
    if (b < 64) { W = Wm; WT = WmT; K = 256; Nn = 256; tile = b; }
    else        { W = Ws; WT = WsT; K = 128; Nn = 256; tile = b - 64; }
    const int ntiles_n = Nn / 32;
    const int n0 = (tile % ntiles_n) * 32;
    const int k0 = (tile / ntiles_n) * 32;
    const int tx = tid & 31, ty = tid >> 5;   // 32 x 8
#pragma unroll
    for (int i = 0; i < 32; i += 8)
      t[ty + i][tx] = W[(size_t)(k0 + ty + i) * Nn + n0 + tx];
    __syncthreads();
#pragma unroll
    for (int i = 0; i < 32; i += 8)
      WT[(size_t)(n0 + ty + i) * K + k0 + tx] = f2bf(t[tx][ty + i]);
  }
}

// ---------------------------------------------------------------------------
// scatter_fused: blocks [0, bNode) do the node pipeline (long pole, launches
// first); blocks [bNode, bNode+bHedge) do the hedge pipeline and fill in
// behind. One wave per receiver node, register accumulate, no atomics.
// ---------------------------------------------------------------------------
__global__ __launch_bounds__(256) void scatter_fused(
    const unsigned short* __restrict__ X,    // [N,256] bf16
    const int* __restrict__ snd1,
    const float* __restrict__ conv1,
    const int* __restrict__ ro1,             // [N+1]
    unsigned short* __restrict__ A,          // [Mp,256] bf16
    float* __restrict__ c1,                  // [Mp]
    const unsigned short* __restrict__ Hf,   // [Nh,128] bf16
    const int* __restrict__ snd2,
    const float* __restrict__ conv2,
    const int* __restrict__ ro2,             // [N+1]
    unsigned short* __restrict__ B,          // [Mp,128] bf16
    float* __restrict__ c2,                  // [Mp]
    int N)
{
  const int lane = threadIdx.x & 63;
  const int bNode = (N + 3) / 4;
  const int bid = (int)blockIdx.x;

  if (bid < bNode) {
    // ---------------- node scatter: C=256, ushort4/lane ----------------
    const int node = __builtin_amdgcn_readfirstlane(
        bid * 4 + ((int)threadIdx.x >> 6));
    if (node >= N) return;
    const int lo = ro1[node];
    const int hi = ro1[node + 1];

    const unsigned short* Xl = X + lane * 4;
    float4 acc = make_float4(0.f, 0.f, 0.f, 0.f);
    float cacc = 0.f;

    int e = lo;
    for (; e + 16 <= hi; e += 16) {          // 16 gathers in flight
      int s[16]; float cv[16]; ushort4 x[16];
#pragma unroll
      for (int j = 0; j < 16; ++j) s[j] = snd1[e + j];
#pragma unroll
      for (int j = 0; j < 16; ++j) cv[j] = conv1[e + j];
#pragma unroll
      for (int j = 0; j < 16; ++j)
        x[j] = *reinterpret_cast<const ushort4*>(Xl + (size_t)s[j] * 256);
#pragma unroll
      for (int j = 0; j < 16; ++j) {
        acc.x = fmaf(cv[j], bf2f(x[j].x), acc.x);
        acc.y = fmaf(cv[j], bf2f(x[j].y), acc.y);
        acc.z = fmaf(cv[j], bf2f(x[j].z), acc.z);
        acc.w = fmaf(cv[j], bf2f(x[j].w), acc.w);
        cacc += cv[j];
      }
    }
    for (; e + 4 <= hi; e += 4) {
      int s[4]; float cv[4]; ushort4 x[4];
#pragma unroll
      for (int j = 0; j < 4; ++j) s[j] = snd1[e + j];
#pragma unroll
      for (int j = 0; j < 4; ++j) cv[j] = conv1[e + j];
#pragma unroll
      for (int j = 0; j < 4; ++j)
        x[j] = *reinterpret_cast<const ushort4*>(Xl + (size_t)s[j] * 256);
#pragma unroll
      for (int j = 0; j < 4; ++j) {
        acc.x = fmaf(cv[j], bf2f(x[j].x), acc.x);
        acc.y = fmaf(cv[j], bf2f(x[j].y), acc.y);
        acc.z = fmaf(cv[j], bf2f(x[j].z), acc.z);
        acc.w = fmaf(cv[j], bf2f(x[j].w), acc.w);
        cacc += cv[j];
      }
    }
    for (; e < hi; ++e) {
      const int s = snd1[e];
      const float cv = conv1[e];
      const ushort4 x = *reinterpret_cast<const ushort4*>(Xl + (size_t)s * 256);
      acc.x = fmaf(cv, bf2f(x.x), acc.x);
      acc.y = fmaf(cv, bf2f(x.y), acc.y);
      acc.z = fmaf(cv, bf2f(x.z), acc.z);
      acc.w = fmaf(cv, bf2f(x.w), acc.w);
      cacc += cv;
    }

    *reinterpret_cast<ushort4*>(A + (size_t)node * 256 + lane * 4) =
        make_ushort4(f2bf(acc.x), f2bf(acc.y), f2bf(acc.z), f2bf(acc.w));
    if (lane == 0) c1[node] = cacc;
  } else {
    // ---------------- hedge scatter: C=128, ushort2/lane ----------------
    const int node = __builtin_amdgcn_readfirstlane(
        (bid - bNode) * 4 + ((int)threadIdx.x >> 6));
    if (node >= N) return;
    const int lo = ro2[node];
    const int hi = ro2[node + 1];

    const unsigned short* Hl = Hf + lane * 2;
    float2 acc = make_float2(0.f, 0.f);
    float cacc = 0.f;

    int e = lo;
    for (; e + 8 <= hi; e += 8) {
      int s[8]; float cv[8]; ushort2 x[8];
#pragma unroll
      for (int j = 0; j < 8; ++j) s[j] = snd2[e + j];
#pragma unroll
      for (int j = 0; j < 8; ++j) cv[j] = conv2[e + j];
#pragma unroll
      for (int j = 0; j < 8; ++j)
        x[j] = *reinterpret_cast<const ushort2*>(Hl + (size_t)s[j] * 128);
#pragma unroll
      for (int j = 0; j < 8; ++j) {
        acc.x = fmaf(cv[j], bf2f(x[j].x), acc.x);
        acc.y = fmaf(cv[j], bf2f(x[j].y), acc.y);
        cacc += cv[j];
      }
    }
    for (; e < hi; ++e) {
      const int s = snd2[e];
      const float cv = conv2[e];
      const ushort2 x = *reinterpret_cast<const ushort2*>(Hl + (size_t)s * 128);
      acc.x = fmaf(cv, bf2f(x.x), acc.x);
      acc.y = fmaf(cv, bf2f(x.y), acc.y);
      cacc += cv;
    }

    *reinterpret_cast<ushort2*>(B + (size_t)node * 128 + lane * 2) =
        make_ushort2(f2bf(acc.x), f2bf(acc.y));
    if (lane == 0) c2[node] = cacc;
  }
}

// ---------------------------------------------------------------------------
// MFMA dual-GEMM + bias + Hadamard, LDS-cached weight slice.
// Grid: (Mp/256, 4). Block = 512 threads = 8 waves; block tile 256 rows x
// 64 cols. Wave owns 32 rows x 64 cols (2 m-sub x 4 n-sub of 16x16).
// mfma_f32_16x16x32_bf16 fragments:
//   A-frag: row = lane&15, k = 8*(lane>>4) + j
//   B-frag: col = lane&15, k = 8*(lane>>4) + j
//   C/D   : col = lane&15, row = 4*(lane>>4) + reg   [m89-verified]
// ---------------------------------------------------------------------------
__global__ __launch_bounds__(512) void gemm_combine_mfma(
    const unsigned short* __restrict__ A,    // [Mp,256] bf16
    const unsigned short* __restrict__ B,    // [Mp,128] bf16
    const float* __restrict__ c1,            // [Mp]
    const float* __restrict__ c2,            // [Mp]
    const unsigned short* __restrict__ WmT,  // [256,256] bf16 (N-major)
    const float* __restrict__ bm,            // [256]
    const unsigned short* __restrict__ WsT,  // [256,128] bf16 (N-major)
    const float* __restrict__ bs,            // [256]
    float* __restrict__ out,                 // [M,256]
    int M)
{
  __shared__ unsigned short lWm[64][264];    // 64 cols x 256 K, +8 pad
  __shared__ unsigned short lWs[64][136];    // 64 cols x 128 K, +8 pad

  const int tid  = (int)threadIdx.x;
  const int lane = tid & 63;
  const int wv   = tid >> 6;          // 0..7
  const int l15  = lane & 15;
  const int lg   = lane >> 4;         // 0..3
  const int m0      = blockIdx.x * 256;
  const int colBlk  = blockIdx.y * 64;

  // ---- stage weight slices into LDS ----
  for (int i = tid; i < 64 * 256 / 8; i += 512) {       // 2048 x 16B
    const int c = i >> 5, k8 = (i & 31) << 3;
    *reinterpret_cast<bf16x8*>(&lWm[c][k8]) =
        *reinterpret_cast<const bf16x8*>(WmT + (size_t)(colBlk + c) * 256 + k8);
  }
  for (int i = tid; i < 64 * 128 / 8; i += 512) {       // 1024 x 16B
    const int c = i >> 4, k8 = (i & 15) << 3;
    *reinterpret_cast<bf16x8*>(&lWs[c][k8]) =
        *reinterpret_cast<const bf16x8*>(WsT + (size_t)(colBlk + c) * 128 + k8);
  }
  __syncthreads();

  const int rowA = m0 + wv * 32 + l15;

  f32x4 accM[2][4];
  f32x4 accS[2][4];
#pragma unroll
  for (int ms = 0; ms < 2; ++ms)
#pragma unroll
    for (int n = 0; n < 4; ++n) {
      accM[ms][n] = (f32x4)0.f;
      accS[ms][n] = (f32x4)0.f;
    }

  // ---- accM = A @ Wm, K = 256 ----
#pragma unroll
  for (int kc = 0; kc < 256; kc += 32) {
    const int ko = kc + lg * 8;
    const bf16x8 a0 = *reinterpret_cast<const bf16x8*>(A + (size_t)rowA * 256 + ko);
    const bf16x8 a1 = *reinterpret_cast<const bf16x8*>(A + (size_t)(rowA + 16) * 256 + ko);
#pragma unroll
    for (int n = 0; n < 4; ++n) {
      const bf16x8 w = *reinterpret_cast<const bf16x8*>(&lWm[l15 + n * 16][ko]);
      accM[0][n] = __builtin_amdgcn_mfma_f32_16x16x32_bf16(a0, w, accM[0][n], 0, 0, 0);
      accM[1][n] = __builtin_amdgcn_mfma_f32_16x16x32_bf16(a1, w, accM[1][n], 0, 0, 0);
    }
  }

  // ---- accS = B @ Ws, K = 128 ----
#pragma unroll
  for (int kc = 0; kc < 128; kc += 32) {
    const int ko = kc + lg * 8;
    const bf16x8 b0 = *reinterpret_cast<const bf16x8*>(B + (size_t)rowA * 128 + ko);
    const bf16x8 b1 = *reinterpret_cast<const bf16x8*>(B + (size_t)(rowA + 16) * 128 + ko);
#pragma unroll
    for (int n = 0; n < 4; ++n) {
      const bf16x8 w = *reinterpret_cast<const bf16x8*>(&lWs[l15 + n * 16][ko]);
      accS[0][n] = __builtin_amdgcn_mfma_f32_16x16x32_bf16(b0, w, accS[0][n], 0, 0, 0);
      accS[1][n] = __builtin_amdgcn_mfma_f32_16x16x32_bf16(b1, w, accS[1][n], 0, 0, 0);
    }
  }

  // ---- epilogue: (accM + c1*bm) .* (accS + c2*bs) ----
  float bmv[4], bsv[4];
#pragma unroll
  for (int n = 0; n < 4; ++n) {
    bmv[n] = bm[colBlk + n * 16 + l15];
    bsv[n] = bs[colBlk + n * 16 + l15];
  }
#pragma unroll
  for (int ms = 0; ms < 2; ++ms) {
    const int rbase = m0 + wv * 32 + ms * 16 + lg * 4;
#pragma unroll
    for (int r = 0; r < 4; ++r) {
      const int row = rbase + r;
      if (row < M) {
        const float k1 = c1[row];
        const float k2 = c2[row];
#pragma unroll
        for (int n = 0; n < 4; ++n) {
          const int col = colBlk + n * 16 + l15;
          const float mv = accM[ms][n][r] + k1 * bmv[n];
          const float sv = accS[ms][n][r] + k2 * bsv[n];
          out[(size_t)row * 256 + col] = mv * sv;
        }
      }
    }
  }
}

extern "C" void kernel_launch(void* const* d_in, const int* in_sizes, int n_in,
                              void* d_out, int out_size, void* d_ws, size_t ws_size,
                              hipStream_t stream) {
  const float* node_features  = (const float*)d_in[0];   // [50000,256]
  const float* hedge_features = (const float*)d_in[1];   // [25000,128]
  const int*   node_senders   = (const int*)d_in[2];     // [E]
  const int*   node_receivers = (const int*)d_in[3];     // [E] sorted
  const float* node_conv      = (const float*)d_in[4];   // [E]
  const int*   h2n_senders    = (const int*)d_in[5];     // [E2]
  const int*   h2n_receivers  = (const int*)d_in[6];     // [E2] sorted
  const float* h2n_conv       = (const float*)d_in[7];   // [E2]
  const float* Wm             = (const float*)d_in[8];   // [256,256]
  const float* bm             = (const float*)d_in[9];   // [256]
  const float* Ws             = (const float*)d_in[10];  // [128,256]
  const float* bs             = (const float*)d_in[11];  // [256]
  float* out = (float*)d_out;

  const int M   = in_sizes[0] / 256;       // 50000 nodes
  const int Nh  = in_sizes[1] / 128;       // 25000 hedges
  const int E   = in_sizes[2];             // 800000
  const int E2  = in_sizes[5];             // 400000
  const int Mp  = ((M + 255) / 256) * 256; // padded rows for 256-row GEMM tiles

  // Workspace layout (bf16 = unsigned short):
  //   A[Mp,256] | B[Mp,128] | Xb[M,256] | Hb[Nh,128] | WmT[256,256] | WsT[256,128]
  //   | c1 f32 [Mp] | c2 f32 [Mp] | ro1 [M+1] | ro2 [M+1]
  unsigned short* Ab  = (unsigned short*)d_ws;
  unsigned short* Bb  = Ab + (size_t)Mp * 256;
  unsigned short* Xb  = Bb + (size_t)Mp * 128;
  unsigned short* Hb  = Xb + (size_t)M * 256;
  unsigned short* WmT = Hb + (size_t)Nh * 128;
  unsigned short* WsT = WmT + 256 * 256;
  float* c1 = (float*)(WsT + 256 * 128);
  float* c2 = c1 + Mp;
  int*   ro1 = (int*)(c2 + Mp);
  int*   ro2 = ro1 + (M + 1);

  const int nX4 = M * 256 / 4, nH4 = Nh * 128 / 4;
  const int bX  = (nX4 + 255) / 256;
  const int bH  = (nH4 + 255) / 256;
  const int bE1 = (E + 255) / 256;
  const int bE2 = (E2 + 255) / 256;
  const int prep_blocks = bX + bH + bE1 + bE2 + 64 + 32;

  prep_all<<<prep_blocks, 256, 0, stream>>>(
      node_features, hedge_features,
      node_receivers, E, h2n_receivers, E2, M,
      Wm, Ws, Xb, Hb, ro1, ro2, WmT, WsT, nX4, nH4);

  const int bNode = (M + 3) / 4;
  scatter_fused<<<bNode * 2, 256, 0, stream>>>(
      Xb, node_senders, node_conv, ro1, Ab, c1,
      Hb, h2n_senders, h2n_conv, ro2, Bb, c2, M);

  gemm_combine_mfma<<<dim3(Mp / 256, 4), 512, 0, stream>>>(
      Ab, Bb, c1, c2, WmT, bm, WsT, bs, out, M);
}